// Round 1
// baseline (253.189 us; speedup 1.0000x reference)
//
#include <hip/hip_runtime.h>

// RotaryEmbedding2D: out[b,s] is a 64x64 block-diagonal rotation matrix.
// B=16, S=1024, D=64, q=16, h=32. BASE=10000, SCALE=1.
// For half-index h in [0,32): angle = (h<16 ? x : y) * 10000^{-(h%16)/16}
// Row 2h:   col 2h = cos, col 2h+1 = -sin
// Row 2h+1: col 2h = sin, col 2h+1 =  cos
// Everything else zero. Output is 256 MiB fp32 -> pure write-BW bound.

#define NBS 16384   // B*S
#define HD  32      // D/2

__global__ __launch_bounds__(256) void rope2d_kernel(
    const float* __restrict__ spa,   // (B,S,2)
    float* __restrict__ out)         // (B,S,64,64)
{
    const int bs = blockIdx.x;   // 0..16383
    const int t  = threadIdx.x;  // 0..255

    __shared__ float ssin[HD];
    __shared__ float scos[HD];

    if (t < HD) {
        // t<16 -> x (spa[...,0]), t>=16 -> y (spa[...,1]); i = t & 15
        const float xy = spa[bs * 2 + (t >> 4)];
        const int   i  = t & 15;
        // inv_freq = 10000^(-i/16) = exp2(-i * log2(10000)/16)
        const float invf = exp2f(-(float)i * 0.83048202372184059f);
        const float a = xy * invf;
        ssin[t] = sinf(a);
        scos[t] = cosf(a);
    }
    __syncthreads();

    // 64x64 fp32 matrix = 1024 float4 groups, row-major: group g -> row g>>4, colgroup g&15
    float4* outv = (float4*)out + (size_t)bs * 1024;

    #pragma unroll
    for (int k = 0; k < 4; ++k) {
        const int g    = t + k * 256;   // consecutive lanes -> consecutive float4: coalesced
        const int row  = g >> 4;
        const int cg   = g & 15;
        float4 v = make_float4(0.f, 0.f, 0.f, 0.f);
        if (cg == (row >> 2)) {         // the single nonzero group in this row
            const int h = row >> 1;
            const float s = ssin[h];
            const float c = scos[h];
            float e0, e1;
            if (row & 1) { e0 = s; e1 = c; }      // odd row:  sin, cos
            else         { e0 = c; e1 = -s; }     // even row: cos, -sin
            if (row & 2) { v.z = e0; v.w = e1; }  // pair offset 2 within group
            else         { v.x = e0; v.y = e1; }  // pair offset 0
        }
        outv[g] = v;
    }
}

extern "C" void kernel_launch(void* const* d_in, const int* in_sizes, int n_in,
                              void* d_out, int out_size, void* d_ws, size_t ws_size,
                              hipStream_t stream) {
    const float* spa = (const float*)d_in[0];
    float* out = (float*)d_out;
    rope2d_kernel<<<NBS, 256, 0, stream>>>(spa, out);
}